// Round 2
// baseline (1388.431 us; speedup 1.0000x reference)
//
#include <hip/hip_runtime.h>
#include <math.h>

#define HH 2048
#define WW 2048
#define NIMG 4
#define NCH 3
#define PLANES (NIMG*NCH)            // 12
#define PIX (HH*WW)                  // 4194304
#define TOT (PLANES*PIX)             // 50331648
#define MED_RANK 25165823u           // floor(0.5*(TOT-1)), method='lower'

struct GW { float w[7]; };

// ---------------- Sobel + structure tensor products ----------------
__global__ __launch_bounds__(256) void sobel_prod(const float* __restrict__ x,
                                                  float* __restrict__ A) {
    int idx = blockIdx.x * 256 + threadIdx.x;          // < 2^24
    int w = idx & (WW - 1);
    int h = (idx >> 11) & (HH - 1);
    int n = idx >> 22;
    const float* xp = x + (size_t)n * PIX;

    auto at = [&](int hh, int ww) -> float {
        if (hh < 0 || hh >= HH || ww < 0 || ww >= WW) return 0.f;
        return xp[hh * WW + ww];
    };
    float a00 = at(h-1, w-1), a01 = at(h-1, w), a02 = at(h-1, w+1);
    float a10 = at(h,   w-1),                  a12 = at(h,   w+1);
    float a20 = at(h+1, w-1), a21 = at(h+1, w), a22 = at(h+1, w+1);

    float Ix = (a02 - a00) + 2.f*(a12 - a10) + (a22 - a20);
    float Iy = (a20 - a00) + 2.f*(a21 - a01) + (a22 - a02);

    size_t base = (size_t)(n * NCH) * PIX + (size_t)h * WW + w;
    A[base]            = Ix * Ix;
    A[base + PIX]      = Iy * Iy;
    A[base + 2 * PIX]  = Ix * Iy;
}

// ---------------- Separable 7-tap Gaussian ----------------
__global__ __launch_bounds__(256) void gauss_h(const float* __restrict__ A,
                                               float* __restrict__ B, GW gw) {
    int idx = blockIdx.x * 256 + threadIdx.x;          // < TOT
    int w = idx & (WW - 1);
    int rowbase = idx - w;
    float s = 0.f;
#pragma unroll
    for (int j = 0; j < 7; j++) {
        int ww2 = w + j - 3;
        if (ww2 >= 0 && ww2 < WW) s += gw.w[j] * A[rowbase + ww2];
    }
    B[idx] = s;
}

__global__ __launch_bounds__(256) void gauss_v(const float* __restrict__ B,
                                               float* __restrict__ A, GW gw) {
    int idx = blockIdx.x * 256 + threadIdx.x;
    int h = (idx >> 11) & (HH - 1);
    float s = 0.f;
#pragma unroll
    for (int j = 0; j < 7; j++) {
        int hh = h + j - 3;
        if (hh >= 0 && hh < HH) s += gw.w[j] * B[idx + (j - 3) * WW];
    }
    A[idx] = s;
}

// ---------------- Radix-select median (exact order statistic) ----------------
__device__ __forceinline__ unsigned f2key(float f) {
    unsigned b = __float_as_uint(f);
    return (b & 0x80000000u) ? ~b : (b | 0x80000000u);
}

// pass 0: bins key>>20 (4096)
// pass 1: filter key>>20 == ctrl[0]; bins (key>>8)&0xFFF (4096)
// pass 2: filter key>>8 == (ctrl[0]<<12)|ctrl[1]; bins key&0xFF (256)
__global__ __launch_bounds__(256) void hist_pass(const float* __restrict__ S,
                                                 unsigned* __restrict__ hist,
                                                 int pass,
                                                 const unsigned* __restrict__ ctrl) {
    __shared__ unsigned lh[4096];
    for (int i = threadIdx.x; i < 4096; i += 256) lh[i] = 0;
    __syncthreads();

    unsigned p1 = 0, p2 = 0;
    if (pass >= 1) p1 = ctrl[0];
    if (pass == 2) p2 = (ctrl[0] << 12) | ctrl[1];

    const float4* S4 = (const float4*)S;
    const long long n4 = TOT / 4;
    long long stride = (long long)gridDim.x * 256;
    for (long long i = (long long)blockIdx.x * 256 + threadIdx.x; i < n4; i += stride) {
        float4 v = S4[i];
        float vv[4] = {v.x, v.y, v.z, v.w};
#pragma unroll
        for (int k = 0; k < 4; k++) {
            unsigned key = f2key(vv[k]);
            if (pass == 0) {
                atomicAdd(&lh[key >> 20], 1u);
            } else if (pass == 1) {
                if ((key >> 20) == p1) atomicAdd(&lh[(key >> 8) & 0xFFFu], 1u);
            } else {
                if ((key >> 8) == p2) atomicAdd(&lh[key & 0xFFu], 1u);
            }
        }
    }
    __syncthreads();
    int nb = (pass == 2) ? 256 : 4096;
    for (int i = threadIdx.x; i < nb; i += 256)
        if (lh[i]) atomicAdd(&hist[i], lh[i]);
}

__global__ __launch_bounds__(256) void select_bucket(const unsigned* __restrict__ hist,
                                                     int nbins,
                                                     const unsigned* __restrict__ rank_in,
                                                     unsigned rank_imm,
                                                     unsigned* __restrict__ bucket_out,
                                                     unsigned* __restrict__ rank_out) {
    __shared__ unsigned cnt[4096];
    __shared__ unsigned csum[256];
    int t = threadIdx.x;
    int per = nbins >> 8;                    // 16 or 1
    for (int i = t; i < nbins; i += 256) cnt[i] = hist[i];
    __syncthreads();
    unsigned s = 0;
    for (int j = 0; j < per; j++) s += cnt[t * per + j];
    csum[t] = s;
    __syncthreads();
    if (t == 0) {
        unsigned r = rank_in ? *rank_in : rank_imm;
        unsigned acc = 0;
        int c = 0;
        for (; c < 256; c++) { if (acc + csum[c] > r) break; acc += csum[c]; }
        int b = c * per;
        for (;; b++) { if (acc + cnt[b] > r) break; acc += cnt[b]; }
        *bucket_out = (unsigned)b;
        *rank_out = r - acc;
    }
}

__global__ void finalize_med(const unsigned* __restrict__ ctrl, float* __restrict__ med_out) {
    unsigned key = (ctrl[0] << 20) | (ctrl[1] << 8) | ctrl[2];
    unsigned b = (key & 0x80000000u) ? (key ^ 0x80000000u) : ~key;
    *med_out = __uint_as_float(b);
}

// ---------------- Optional standalone threshold (fallback path) ----------------
__global__ __launch_bounds__(256) void thresh_apply(float* __restrict__ A,
                                                    const float* __restrict__ medp) {
    float med = *medp;
    long long i = (long long)blockIdx.x * 256 + threadIdx.x;
    float4* A4 = (float4*)A;
    float4 v = A4[i];
    v.x = (v.x > med) ? v.x : 0.f;
    v.y = (v.y > med) ? v.y : 0.f;
    v.z = (v.z > med) ? v.z : 0.f;
    v.w = (v.w > med) ? v.w : 0.f;
    A4[i] = v;
}

// ---------------- Threshold + 7x7 NMS + mask ----------------
#define BX 32
#define BY 8
__global__ __launch_bounds__(BX*BY) void nms_kernel(const float* __restrict__ S,
                                                    const float* __restrict__ medp,
                                                    float* __restrict__ out) {
    __shared__ float tile[BY + 6][BX + 6];
    float med = medp ? *medp : -INFINITY;   // fallback path: threshold pre-applied
    int plane = blockIdx.z;
    int bx = blockIdx.x * BX, by = blockIdx.y * BY;
    const float* Sp = S + (size_t)plane * PIX;

    for (int i = threadIdx.y * BX + threadIdx.x; i < (BY + 6) * (BX + 6); i += BX * BY) {
        int r = i / (BX + 6), c = i % (BX + 6);
        int gh = by + r - 3, gw = bx + c - 3;
        float v = -INFINITY;                 // reduce_window init: OOB never wins
        if (gh >= 0 && gh < HH && gw >= 0 && gw < WW) {
            float s = Sp[(size_t)gh * WW + gw];
            v = (s > med) ? s : 0.f;
        }
        tile[r][c] = v;
    }
    __syncthreads();

    int tx = threadIdx.x, ty = threadIdx.y;
    float c0 = tile[ty + 3][tx + 3];
    float m = -INFINITY;
#pragma unroll
    for (int dr = 0; dr < 7; dr++)
#pragma unroll
        for (int dc = 0; dc < 7; dc++)
            m = fmaxf(m, tile[ty + dr][tx + dc]);

    float o = (c0 == m) ? c0 : 0.f;
    out[(size_t)plane * PIX + (size_t)(by + ty) * WW + (bx + tx)] = o;
}

// ---------------- Launch ----------------
extern "C" void kernel_launch(void* const* d_in, const int* in_sizes, int n_in,
                              void* d_out, int out_size, void* d_ws, size_t ws_size,
                              hipStream_t stream) {
    const float* x = (const float*)d_in[0];
    float* out = (float*)d_out;

    // d_ws usage: exactly TOT floats (S buffer). Nothing else unless ws_size allows.
    float* A = (float*)d_ws;

    // Histograms live in d_out (dead between gauss_v and nms overwrite):
    // hist1 [0,4096) | hist2 [4096,8192) | hist3 [8192,8448) | dctrl [8448,8456)
    unsigned* hist1 = (unsigned*)d_out;
    unsigned* hist2 = hist1 + 4096;
    unsigned* hist3 = hist2 + 4096;
    unsigned* dctrl = hist3 + 256;

    // ctrl block (8 u32): prefer d_ws tail iff workspace has room (constant per
    // process -> graph-safe branch). Otherwise ctrl stays in d_out and we run a
    // separate threshold pass so nms never reads d_out while writing it.
    bool ws_ctrl = ws_size >= (size_t)TOT * 4 + 256;
    unsigned* ctrl = ws_ctrl ? (unsigned*)((char*)d_ws + (size_t)TOT * 4) : dctrl;
    // ctrl: [0]=b1 [1]=b2 [2]=b3 [3]=rank2 [4]=rank3 [5]=med(float bits) [6]=scratch

    // Gaussian weights: 1D normalized (== row sums of reference's normalized 2D kernel)
    GW gw;
    {
        double g[7], s = 0.0;
        for (int i = 0; i < 7; i++) { double r = i - 3.0; g[i] = exp(-r * r / 50.0); s += g[i]; }
        for (int i = 0; i < 7; i++) gw.w[i] = (float)(g[i] / s);
    }

    // 1. Sobel + products: x -> A
    sobel_prod<<<NIMG * PIX / 256, 256, 0, stream>>>(x, A);
    // 2. Gaussian: A -> out(scratch) -> A
    gauss_h<<<TOT / 256, 256, 0, stream>>>(A, out, gw);
    gauss_v<<<TOT / 256, 256, 0, stream>>>(out, A, gw);
    // d_out now scratch: zero the histogram region (re-done every call/replay)
    hipMemsetAsync(d_out, 0, (4096 + 4096 + 256 + 8) * sizeof(unsigned), stream);
    // 3. Exact median (3-pass radix select), hists in d_out, ctrl per layout
    hist_pass<<<8192, 256, 0, stream>>>(A, hist1, 0, ctrl);
    select_bucket<<<1, 256, 0, stream>>>(hist1, 4096, nullptr, MED_RANK, &ctrl[0], &ctrl[3]);
    hist_pass<<<8192, 256, 0, stream>>>(A, hist2, 1, ctrl);
    select_bucket<<<1, 256, 0, stream>>>(hist2, 4096, &ctrl[3], 0u, &ctrl[1], &ctrl[4]);
    hist_pass<<<8192, 256, 0, stream>>>(A, hist3, 2, ctrl);
    select_bucket<<<1, 256, 0, stream>>>(hist3, 256, &ctrl[4], 0u, &ctrl[2], &ctrl[6]);
    finalize_med<<<1, 1, 0, stream>>>(ctrl, (float*)&ctrl[5]);

    // 4. Threshold + NMS + mask
    dim3 grid(WW / BX, HH / BY, PLANES);
    dim3 block(BX, BY);
    if (ws_ctrl) {
        // med lives in d_ws tail -> safe to read while writing d_out
        nms_kernel<<<grid, block, 0, stream>>>(A, (const float*)&ctrl[5], out);
    } else {
        // med lives in d_out -> apply threshold to A first, then NMS without med
        thresh_apply<<<TOT / 4 / 256, 256, 0, stream>>>(A, (const float*)&ctrl[5]);
        nms_kernel<<<grid, block, 0, stream>>>(A, nullptr, out);
    }
}